// Round 1
// baseline (742.441 us; speedup 1.0000x reference)
//
#include <hip/hip_runtime.h>
#include <hip/hip_bf16.h>
#include <math.h>

typedef __bf16 bf16x8 __attribute__((ext_vector_type(8)));
typedef float f32x4 __attribute__((ext_vector_type(4)));

#define TLEN 512
#define FIN 5
#define BT 16   // batch tile per block
#define TT 64   // time chunk staged in LDS

__device__ __forceinline__ float sigmoid_f(float x) {
    return __fdividef(1.f, 1.f + __expf(-x));
}
__device__ __forceinline__ float tanh_f(float x) {
    float ax = fabsf(x);
    float e = __expf(-2.f * ax);
    float r = __fdividef(1.f - e, 1.f + e);
    return copysignf(r, x);
}
__device__ __forceinline__ f32x4 splat4(float v) { f32x4 r = {v, v, v, v}; return r; }

// One block: 16 batches, 4 waves. Wave w owns hidden slice [16w, 16w+16).
// Lane l: hh = 16w + (l&15); batches b0g + (l>>4)*4 + {0..3} (MFMA C-layout rows).
// h state lives in registers (f32x4 over the 4 batches) for lane's hh.
__global__ __launch_bounds__(256, 1) void grut1_kernel(
    const float* __restrict__ X, const float* __restrict__ dtp,
    const float* __restrict__ w_ih, const float* __restrict__ w_hh,
    const float* __restrict__ b_ih, const float* __restrict__ b_hh,
    const float* __restrict__ w_dt, const float* __restrict__ b_dt,
    const float* __restrict__ w_out, const float* __restrict__ b_out,
    float* __restrict__ out)
{
    // A-operand buffers in MFMA fragment-linear layout:
    // element idx = kt*512 + lf*8 + jj  (lf = frag lane, jj = within-lane k)
    __shared__ __align__(16) __bf16 Ahi[2 * 64 * 8];
    __shared__ __align__(16) __bf16 Alo[2 * 64 * 8];
    // X chunk: [r = t_local*5 + f][b], stride 20 (16 batches + pad) -> conflict-free b128 reads
    __shared__ __align__(16) float Xs[FIN * TT * 20];
    __shared__ __align__(16) float DTs[TT * 20];
    __shared__ __align__(16) float PP[64];   // [wave][b] pred partials

    const int tid = threadIdx.x;
    const int w = tid >> 6;
    const int l = tid & 63;
    const int lane16 = l & 15;
    const int quad = l >> 4;
    const int B0 = quad * 4;
    const int hh = w * 16 + lane16;
    const int b0g = blockIdx.x * BT;

    // A-write position for k = hh
    const int kt_w = hh >> 5;
    const int kk = hh & 31;
    const int q2 = kk >> 3;
    const int jj = kk & 7;

    // per-lane constants
    const float wdt = w_dt[hh];
    const float bdt = b_dt[hh];
    const float wout = w_out[hh];
    const float bout = b_out[0];
    const float bias_r = b_ih[hh] + b_hh[hh];
    const float bias_z = b_ih[64 + hh] + b_hh[64 + hh];
    const float bias_ni = b_ih[128 + hh];
    const float bias_nh = b_hh[128 + hh];   // stays inside r*(...) per PyTorch GRU semantics
    float wih_r[5], wih_z[5], wih_n[5];
#pragma unroll
    for (int f = 0; f < 5; ++f) {
        wih_r[f] = w_ih[hh * 5 + f];
        wih_z[f] = w_ih[(64 + hh) * 5 + f];
        wih_n[f] = w_ih[(128 + hh) * 5 + f];
    }

    // B fragments (w_hh), hi/lo bf16 split, resident in VGPRs for the whole kernel.
    // B[k][n]: n = lane&15 -> j = g*64 + hh ; k = kt*32 + quad*8 + i
    bf16x8 Bh[3][2], Bl[3][2];
#pragma unroll
    for (int g = 0; g < 3; ++g) {
        const int j = g * 64 + hh;
#pragma unroll
        for (int kt = 0; kt < 2; ++kt) {
            const int k0 = kt * 32 + quad * 8;
            const float* src = w_hh + j * 64 + k0;
            bf16x8 hi, lo;
#pragma unroll
            for (int i = 0; i < 8; ++i) {
                float v = src[i];
                __bf16 h = (__bf16)v;
                hi[i] = h;
                lo[i] = (__bf16)(v - (float)h);
            }
            Bh[g][kt] = hi;
            Bl[g][kt] = lo;
        }
    }

    f32x4 hreg = {0.f, 0.f, 0.f, 0.f};

    for (int t = 0; t < TLEN; ++t) {
        const int tl = t & (TT - 1);
        if (tl == 0) {
            __syncthreads();
            // stage X chunk: 16 batches x 64 t x 5 f = 1280 float4, coalesced per-batch runs
#pragma unroll
            for (int i = 0; i < 5; ++i) {
                int v = i * 256 + tid;
                int b = v / 80;            // 80 float4 per batch (320 floats)
                int rem = v - b * 80;
                const float* gp = X + ((size_t)(b0g + b) * TLEN + t) * FIN + rem * 4;
                float4 xv = *(const float4*)gp;
                int rb = rem * 4;
                Xs[(rb + 0) * 20 + b] = xv.x;
                Xs[(rb + 1) * 20 + b] = xv.y;
                Xs[(rb + 2) * 20 + b] = xv.z;
                Xs[(rb + 3) * 20 + b] = xv.w;
            }
            {
                int b = tid >> 4;
                int rem = tid & 15;
                const float* gp = dtp + (size_t)(b0g + b) * TLEN + t + rem * 4;
                float4 dv = *(const float4*)gp;
                DTs[(rem * 4 + 0) * 20 + b] = dv.x;
                DTs[(rem * 4 + 1) * 20 + b] = dv.y;
                DTs[(rem * 4 + 2) * 20 + b] = dv.z;
                DTs[(rem * 4 + 3) * 20 + b] = dv.w;
            }
            __syncthreads();
        }

        // --- h_tilde = exp(-relu(dt*wdt + bdt)) * h_prev, + bf16 hi/lo pack ---
        f32x4 dtv = *(const f32x4*)&DTs[tl * 20 + B0];
        f32x4 htl;
        __bf16 phi[4], plo[4];
#pragma unroll
        for (int r = 0; r < 4; ++r) {
            float d = fmaxf(dtv[r] * wdt + bdt, 0.f);
            float e = __expf(-d);
            float v = e * hreg[r];
            htl[r] = v;
            __bf16 h = (__bf16)v;
            phi[r] = h;
            plo[r] = (__bf16)(v - (float)h);
        }
        __syncthreads();   // prior iteration's A reads complete
#pragma unroll
        for (int r = 0; r < 4; ++r) {
            int idx = kt_w * 512 + (q2 * 16 + B0 + r) * 8 + jj;
            Ahi[idx] = phi[r];
            Alo[idx] = plo[r];
        }
        __syncthreads();   // A buffer visible

        // --- gh = h_tilde @ w_hh^T via MFMA (3-term hi/lo split) ---
        bf16x8 Ah0 = *(const bf16x8*)&Ahi[l * 8];
        bf16x8 Ah1 = *(const bf16x8*)&Ahi[512 + l * 8];
        bf16x8 Al0 = *(const bf16x8*)&Alo[l * 8];
        bf16x8 Al1 = *(const bf16x8*)&Alo[512 + l * 8];

        f32x4 acc[3];
#pragma unroll
        for (int g = 0; g < 3; ++g) {
            f32x4 a = {0.f, 0.f, 0.f, 0.f};
            a = __builtin_amdgcn_mfma_f32_16x16x32_bf16(Ah0, Bh[g][0], a, 0, 0, 0);
            a = __builtin_amdgcn_mfma_f32_16x16x32_bf16(Ah1, Bh[g][1], a, 0, 0, 0);
            a = __builtin_amdgcn_mfma_f32_16x16x32_bf16(Al0, Bh[g][0], a, 0, 0, 0);
            a = __builtin_amdgcn_mfma_f32_16x16x32_bf16(Al1, Bh[g][1], a, 0, 0, 0);
            a = __builtin_amdgcn_mfma_f32_16x16x32_bf16(Ah0, Bl[g][0], a, 0, 0, 0);
            a = __builtin_amdgcn_mfma_f32_16x16x32_bf16(Ah1, Bl[g][1], a, 0, 0, 0);
            acc[g] = a;
        }

        // --- gi = x @ w_ih^T (exact fp32), gates, h_new ---
        f32x4 gr = splat4(bias_r), gz = splat4(bias_z), gn = splat4(bias_ni);
#pragma unroll
        for (int f = 0; f < 5; ++f) {
            f32x4 xv = *(const f32x4*)&Xs[(tl * 5 + f) * 20 + B0];
            gr += splat4(wih_r[f]) * xv;
            gz += splat4(wih_z[f]) * xv;
            gn += splat4(wih_n[f]) * xv;
        }
        gr += acc[0];
        gz += acc[1];

        f32x4 hnew, p;
#pragma unroll
        for (int r = 0; r < 4; ++r) {
            float rr = sigmoid_f(gr[r]);
            float zz = sigmoid_f(gz[r]);
            float nn = tanh_f(gn[r] + rr * (acc[2][r] + bias_nh));
            float hv = (1.f - zz) * nn + zz * htl[r];
            hnew[r] = hv;
            p[r] = wout * hv;
        }
        hreg = hnew;

        // --- pred: reduce over hidden dim (16 lanes in-wave, then cross-wave LDS) ---
#pragma unroll
        for (int m = 1; m <= 8; m <<= 1) {
#pragma unroll
            for (int r = 0; r < 4; ++r) p[r] += __shfl_xor(p[r], m, 64);
        }
        if (lane16 == 0) *(f32x4*)&PP[w * 16 + B0] = p;
        __syncthreads();
        if (tid < 16) {
            float s = PP[tid] + PP[16 + tid] + PP[32 + tid] + PP[48 + tid] + bout;
            out[(size_t)(b0g + tid) * TLEN + t] = s;
        }
    }
}

extern "C" void kernel_launch(void* const* d_in, const int* in_sizes, int n_in,
                              void* d_out, int out_size, void* d_ws, size_t ws_size,
                              hipStream_t stream) {
    const float* X    = (const float*)d_in[0];
    const float* dt   = (const float*)d_in[1];
    const float* w_ih = (const float*)d_in[2];
    const float* w_hh = (const float*)d_in[3];
    const float* b_ih = (const float*)d_in[4];
    const float* b_hh = (const float*)d_in[5];
    const float* w_dt = (const float*)d_in[6];
    const float* b_dt = (const float*)d_in[7];
    const float* w_out = (const float*)d_in[8];
    const float* b_out = (const float*)d_in[9];
    float* out = (float*)d_out;

    grut1_kernel<<<dim3(4096 / BT), dim3(256), 0, stream>>>(
        X, dt, w_ih, w_hh, b_ih, b_hh, w_dt, b_dt, w_out, b_out, out);
}

// Round 2
// 702.637 us; speedup vs baseline: 1.0567x; 1.0567x over previous
//
#include <hip/hip_runtime.h>
#include <hip/hip_bf16.h>
#include <math.h>

typedef __bf16 bf16x8 __attribute__((ext_vector_type(8)));
typedef float f32x4 __attribute__((ext_vector_type(4)));

#define TLEN 512
#define FIN 5
#define BT 16   // batch tile per block

__device__ __forceinline__ float sigmoid_f(float x) {
    return __fdividef(1.f, 1.f + __expf(-x));
}
__device__ __forceinline__ float tanh_f(float x) {
    float ax = fabsf(x);
    float e = __expf(-2.f * ax);
    float r = __fdividef(1.f - e, 1.f + e);
    return copysignf(r, x);
}

// 256 blocks x 256 threads. Block: 16 batches; wave w owns hidden [16w,16w+16).
// Lane: hh = 16w + (l&15); batches B0..B0+3 (B0 = (l>>4)*4) -- MFMA C-layout rows.
// One barrier per timestep: A-frag LDS is double-buffered (phase = t&1).
// X/dt read directly from global (L1 broadcast), prefetched 1 step ahead,
// issued AFTER the barrier so the pre-barrier vmcnt(0) drain never waits on them.
__global__ __launch_bounds__(256, 1) void grut1_kernel(
    const float* __restrict__ X, const float* __restrict__ dtp,
    const float* __restrict__ w_ih, const float* __restrict__ w_hh,
    const float* __restrict__ b_ih, const float* __restrict__ b_hh,
    const float* __restrict__ w_dt, const float* __restrict__ b_dt,
    const float* __restrict__ w_out, const float* __restrict__ b_out,
    float* __restrict__ out)
{
    // A buffers: [phase(2)][hi/lo(2)][ktile(2)][512 elem] = 4096 bf16 = 8 KB
    __shared__ __align__(16) __bf16 As[4096];
    // pred partials: [wave(4)][batch(16)][tq(4)]
    __shared__ __align__(16) float PP4[256];

    const int tid = threadIdx.x;
    const int w = tid >> 6;
    const int l = tid & 63;
    const int lane16 = l & 15;
    const int quad = l >> 4;
    const int B0 = quad * 4;
    const int hh = w * 16 + lane16;
    const int b0g = blockIdx.x * BT;

    // A-frag write position for k = hh (fragment-linear, verified R1)
    const int kt_w = hh >> 5;
    const int kk = hh & 31;
    const int ew = kt_w * 512 + ((kk >> 3) * 16 + B0) * 8 + (kk & 7);

    // per-lane constants
    const float wdt = w_dt[hh];
    const float bdt = b_dt[hh];
    const float wout = w_out[hh];
    const float bout = b_out[0];
    const float bias_r = b_ih[hh] + b_hh[hh];
    const float bias_z = b_ih[64 + hh] + b_hh[64 + hh];
    const float bias_ni = b_ih[128 + hh];
    const float bias_nh = b_hh[128 + hh];
    float wih_r[5], wih_z[5], wih_n[5];
#pragma unroll
    for (int f = 0; f < 5; ++f) {
        wih_r[f] = w_ih[hh * 5 + f];
        wih_z[f] = w_ih[(64 + hh) * 5 + f];
        wih_n[f] = w_ih[(128 + hh) * 5 + f];
    }

    // B fragments (w_hh) hi/lo bf16 split, VGPR-resident.
    bf16x8 Bh[3][2], Bl[3][2];
#pragma unroll
    for (int g = 0; g < 3; ++g) {
        const int j = g * 64 + hh;
#pragma unroll
        for (int kt = 0; kt < 2; ++kt) {
            const float* src = w_hh + j * 64 + kt * 32 + quad * 8;
            bf16x8 hi, lo;
#pragma unroll
            for (int i = 0; i < 8; ++i) {
                float v = src[i];
                __bf16 h = (__bf16)v;
                hi[i] = h;
                lo[i] = (__bf16)(v - (float)h);
            }
            Bh[g][kt] = hi;
            Bl[g][kt] = lo;
        }
    }

    // global pointers: 4 batches per lane
    const float* xp[4];
    const float* dp[4];
#pragma unroll
    for (int r = 0; r < 4; ++r) {
        xp[r] = X + (size_t)(b0g + B0 + r) * TLEN * FIN;
        dp[r] = dtp + (size_t)(b0g + B0 + r) * TLEN;
    }

    // prefetch banks (indices all compile-time under unroll)
    float4 xa[2][4];
    float xe[2][4];
    float dv[2][4];
#pragma unroll
    for (int r = 0; r < 4; ++r) {
        xa[0][r] = *(const float4*)(xp[r]);
        xe[0][r] = xp[r][4];
        dv[0][r] = dp[r][0];
    }

    f32x4 hreg = {0.f, 0.f, 0.f, 0.f};
    float pbuf[4][4];

#pragma unroll 1
    for (int tb = 0; tb < TLEN; tb += 4) {
#pragma unroll
        for (int sub = 0; sub < 4; ++sub) {
            const int t = tb + sub;
            const int cu = sub & 1;
            const int nx = cu ^ 1;
            const int pA = (sub & 1) * 2048;

            // ---- pre-barrier: h_tilde + bf16 hi/lo pack + A writes (LDS only) ----
            f32x4 htl;
            __bf16 phi[4], plo[4];
#pragma unroll
            for (int r = 0; r < 4; ++r) {
                float d = fmaxf(dv[cu][r] * wdt + bdt, 0.f);
                float e = __expf(-d);
                float v = e * hreg[r];
                htl[r] = v;
                __bf16 h = (__bf16)v;
                phi[r] = h;
                plo[r] = (__bf16)(v - (float)h);
            }
#pragma unroll
            for (int r = 0; r < 4; ++r) {
                As[pA + ew + r * 8] = phi[r];
                As[pA + 1024 + ew + r * 8] = plo[r];
            }

            __syncthreads();

            // ---- post-barrier region: all VMEM lives here ----
            // combine previous 4-t group's pred partials (wave 0 only)
            if (sub == 0 && tb > 0 && tid < 64) {
                float s = PP4[tid] + PP4[64 + tid] + PP4[128 + tid] + PP4[192 + tid];
                out[(size_t)(b0g + (tid >> 2)) * TLEN + (tb - 4) + (tid & 3)] = s + bout;
            }

            // prefetch t+1 (imm offsets; consumed next step before next barrier)
            if (t + 1 < TLEN) {
#pragma unroll
                for (int r = 0; r < 4; ++r) {
                    xa[nx][r] = *(const float4*)(xp[r] + (sub + 1) * FIN);
                    xe[nx][r] = xp[r][(sub + 1) * FIN + 4];
                    dv[nx][r] = dp[r][sub + 1];
                }
            }

            // A fragments
            bf16x8 Ah0 = *(const bf16x8*)&As[pA + l * 8];
            bf16x8 Ah1 = *(const bf16x8*)&As[pA + 512 + l * 8];
            bf16x8 Al0 = *(const bf16x8*)&As[pA + 1024 + l * 8];
            bf16x8 Al1 = *(const bf16x8*)&As[pA + 1536 + l * 8];

            // gh via MFMA: 3 gates x (2 chains of depth 3) + add
            f32x4 acc[3];
#pragma unroll
            for (int g = 0; g < 3; ++g) {
                f32x4 c1 = {0.f, 0.f, 0.f, 0.f};
                f32x4 c2 = {0.f, 0.f, 0.f, 0.f};
                c1 = __builtin_amdgcn_mfma_f32_16x16x32_bf16(Ah0, Bl[g][0], c1, 0, 0, 0);
                c1 = __builtin_amdgcn_mfma_f32_16x16x32_bf16(Al0, Bh[g][0], c1, 0, 0, 0);
                c1 = __builtin_amdgcn_mfma_f32_16x16x32_bf16(Ah0, Bh[g][0], c1, 0, 0, 0);
                c2 = __builtin_amdgcn_mfma_f32_16x16x32_bf16(Ah1, Bl[g][1], c2, 0, 0, 0);
                c2 = __builtin_amdgcn_mfma_f32_16x16x32_bf16(Al1, Bh[g][1], c2, 0, 0, 0);
                c2 = __builtin_amdgcn_mfma_f32_16x16x32_bf16(Ah1, Bh[g][1], c2, 0, 0, 0);
                acc[g] = c1 + c2;
            }

            // gates (exact fp32 gi) + h update + pred partial
            float pr[4];
#pragma unroll
            for (int r = 0; r < 4; ++r) {
                float4 xv = xa[cu][r];
                float x4 = xe[cu][r];
                float gr = fmaf(wih_r[4], x4, fmaf(wih_r[3], xv.w, fmaf(wih_r[2], xv.z,
                           fmaf(wih_r[1], xv.y, fmaf(wih_r[0], xv.x, bias_r)))));
                float gz = fmaf(wih_z[4], x4, fmaf(wih_z[3], xv.w, fmaf(wih_z[2], xv.z,
                           fmaf(wih_z[1], xv.y, fmaf(wih_z[0], xv.x, bias_z)))));
                float gn = fmaf(wih_n[4], x4, fmaf(wih_n[3], xv.w, fmaf(wih_n[2], xv.z,
                           fmaf(wih_n[1], xv.y, fmaf(wih_n[0], xv.x, bias_ni)))));
                float rr = sigmoid_f(gr + acc[0][r]);
                float zz = sigmoid_f(gz + acc[1][r]);
                float nn = tanh_f(gn + rr * (acc[2][r] + bias_nh));
                float hv = (1.f - zz) * nn + zz * htl[r];
                hreg[r] = hv;
                pr[r] = wout * hv;
            }

            // 16-lane butterfly reduce over hidden slice
#pragma unroll
            for (int m = 1; m <= 8; m <<= 1) {
#pragma unroll
                for (int r = 0; r < 4; ++r) pr[r] += __shfl_xor(pr[r], m, 64);
            }
#pragma unroll
            for (int r = 0; r < 4; ++r) pbuf[r][sub] = pr[r];

            if (sub == 3 && lane16 == 0) {
#pragma unroll
                for (int r = 0; r < 4; ++r) {
                    *(float4*)&PP4[(w * 16 + B0 + r) * 4] =
                        make_float4(pbuf[r][0], pbuf[r][1], pbuf[r][2], pbuf[r][3]);
                }
            }
        }
#pragma unroll
        for (int r = 0; r < 4; ++r) {
            xp[r] += 4 * FIN;
            dp[r] += 4;
        }
    }

    // final 4-t group combine
    __syncthreads();
    if (tid < 64) {
        float s = PP4[tid] + PP4[64 + tid] + PP4[128 + tid] + PP4[192 + tid];
        out[(size_t)(b0g + (tid >> 2)) * TLEN + (TLEN - 4) + (tid & 3)] = s + bout;
    }
}

extern "C" void kernel_launch(void* const* d_in, const int* in_sizes, int n_in,
                              void* d_out, int out_size, void* d_ws, size_t ws_size,
                              hipStream_t stream) {
    const float* X    = (const float*)d_in[0];
    const float* dt   = (const float*)d_in[1];
    const float* w_ih = (const float*)d_in[2];
    const float* w_hh = (const float*)d_in[3];
    const float* b_ih = (const float*)d_in[4];
    const float* b_hh = (const float*)d_in[5];
    const float* w_dt = (const float*)d_in[6];
    const float* b_dt = (const float*)d_in[7];
    const float* w_out = (const float*)d_in[8];
    const float* b_out = (const float*)d_in[9];
    float* out = (float*)d_out;

    grut1_kernel<<<dim3(4096 / BT), dim3(256), 0, stream>>>(
        X, dt, w_ih, w_hh, b_ih, b_hh, w_dt, b_dt, w_out, b_out, out);
}

// Round 4
// 659.105 us; speedup vs baseline: 1.1264x; 1.0660x over previous
//
#include <hip/hip_runtime.h>
#include <hip/hip_bf16.h>
#include <math.h>

typedef __bf16 bf16x8 __attribute__((ext_vector_type(8)));
typedef float f32x4 __attribute__((ext_vector_type(4)));

#define TLEN 512
#define FIN 5
#define BT 16

#define MFMA(a,b,c) __builtin_amdgcn_mfma_f32_16x16x32_bf16(a,b,c,0,0,0)

__device__ __forceinline__ float sigmoid_f(float x) {
    return __fdividef(1.f, 1.f + __expf(-x));
}
__device__ __forceinline__ float tanh_f(float x) {
    float ax = fabsf(x);
    float e = __expf(-2.f * ax);
    float r = __fdividef(1.f - e, 1.f + e);
    return copysignf(r, x);
}

// 256 blocks x 256 threads. Block: 16 batches; wave w owns hidden [16w,16w+16).
// MFMA K=96: k 0..63 = h_tilde (hi/lo planes, 3-term split), k 64..95 = x-tile:
//   slots 64..68 = x features (hi/lo), slot 69 = const 1.0 (bias column), 70..95 = 0.
// X staged per-8-step chunk in A-frag layout, double-buffered by chunk parity.
// Decay exp(-relu(dt*w+b)) precomputed per chunk into regs (off the h-chain).
// R4 fix: ones-column write moved AFTER the zero-init barrier (R3 had a
// zero-vs-ones intra-block race that randomly wiped gate biases).
__global__ __launch_bounds__(256, 1) void grut1_kernel(
    const float* __restrict__ X, const float* __restrict__ dtp,
    const float* __restrict__ w_ih, const float* __restrict__ w_hh,
    const float* __restrict__ b_ih, const float* __restrict__ b_hh,
    const float* __restrict__ w_dt, const float* __restrict__ b_dt,
    const float* __restrict__ w_out, const float* __restrict__ b_out,
    float* __restrict__ out)
{
    __shared__ __align__(16) __bf16 As[4096];    // h~ frags: [phase2][hi/lo][kt2][512]
    __shared__ __align__(16) __bf16 Ax[16384];   // x frags: [parity2][t8][hi512|lo512]
    __shared__ __align__(16) float PP4[256];     // pred partials [wave][m][tq]

    const int tid = threadIdx.x;
    const int w = tid >> 6;
    const int l = tid & 63;
    const int lane16 = l & 15;
    const int quad = l >> 4;
    const int B0 = quad * 4;
    const int hh = w * 16 + lane16;
    const int b0g = blockIdx.x * BT;

    // A-frag write position for k = hh (fragment-linear, verified R1/R2)
    const int ew = (hh >> 5) * 512 + ((((hh & 31) >> 3) * 16) + B0) * 8 + (hh & 7);

    // per-lane constants
    const float wdt = w_dt[hh];
    const float bdt = b_dt[hh];
    const float wout = w_out[hh];
    const float bout = b_out[0];
    const float bias_nh = b_hh[128 + hh];

    // B fragments: [gate][ktile 0..2], hi/lo split, VGPR-resident.
    bf16x8 Bh[3][3], Bl[3][3];
#pragma unroll
    for (int g = 0; g < 3; ++g) {
        const int j = g * 64 + hh;
#pragma unroll
        for (int kt = 0; kt < 2; ++kt) {
            const float* src = w_hh + j * 64 + kt * 32 + quad * 8;
            bf16x8 hi, lo;
#pragma unroll
            for (int i = 0; i < 8; ++i) {
                float v = src[i];
                __bf16 h = (__bf16)v;
                hi[i] = h;
                lo[i] = (__bf16)(v - (float)h);
            }
            Bh[g][kt] = hi;
            Bl[g][kt] = lo;
        }
        // ktile 2: x columns + bias(ones) column; only quad 0 covers k 64..71
        float biasg = (g == 2) ? b_ih[j] : (b_ih[j] + b_hh[j]);
        bf16x8 hi, lo;
#pragma unroll
        for (int i = 0; i < 8; ++i) {
            float v = 0.f;
            if (quad == 0) {
                if (i < 5) v = w_ih[j * 5 + i];
                else if (i == 5) v = biasg;
            }
            __bf16 h = (__bf16)v;
            hi[i] = h;
            lo[i] = (__bf16)(v - (float)h);
        }
        Bh[g][2] = hi;
        Bl[g][2] = lo;
    }

    // x staging map: element v in [0,640) -> (b = v/40, rem = v%40, t = rem/5, f = rem%5)
    int xg[3], xw[3], xvalid[3];
#pragma unroll
    for (int i = 0; i < 3; ++i) {
        int v = tid + i * 256;
        xvalid[i] = (v < 640);
        int vv = xvalid[i] ? v : 0;
        int b = vv / 40;
        int rem = vv - b * 40;
        int tt = rem / 5;
        int f = rem - tt * 5;
        xg[i] = (b0g + b) * (TLEN * FIN) + rem;
        xw[i] = tt * 1024 + b * 8 + f;
    }

    // ---- init: zero Ax, barrier, THEN ones column + chunk-0 x staging ----
    {
        float4 z4 = make_float4(0.f, 0.f, 0.f, 0.f);
        float4* p4 = (float4*)Ax;
#pragma unroll
        for (int i = 0; i < 8; ++i) p4[tid + i * 256] = z4;
    }
    __syncthreads();
    // ones column: slot f=5 in hi plane, every (parity,t,m). No collision with
    // x staging (f<5) or lo plane; chunk publishes never touch slot 5.
    Ax[(tid >> 4) * 1024 + (tid & 15) * 8 + 5] = (__bf16)1.0f;
#pragma unroll
    for (int i = 0; i < 3; ++i) if (xvalid[i]) {
        float v = X[xg[i]];
        __bf16 h = (__bf16)v;
        Ax[xw[i]] = h;
        Ax[512 + xw[i]] = (__bf16)(v - (float)h);
    }

    // decay for chunk 0
    float dtn[32], dec[32];
#pragma unroll
    for (int r = 0; r < 4; ++r) {
        *(float4*)&dtn[r * 8]     = *(const float4*)(dtp + (size_t)(b0g + B0 + r) * TLEN);
        *(float4*)&dtn[r * 8 + 4] = *(const float4*)(dtp + (size_t)(b0g + B0 + r) * TLEN + 4);
    }
#pragma unroll
    for (int t2 = 0; t2 < 8; ++t2)
#pragma unroll
        for (int r = 0; r < 4; ++r)
            dec[t2 * 4 + r] = __expf(-fmaxf(fmaf(dtn[r * 8 + t2], wdt, bdt), 0.f));

    __syncthreads();

    f32x4 hreg = {0.f, 0.f, 0.f, 0.f};
    float pbuf[4][4];
    float xst[3];

#pragma unroll 1
    for (int tb = 0; tb < TLEN; tb += 8) {
        const int par = (tb >> 3) & 1;
        const int npar = par ^ 1;
#pragma unroll
        for (int sub = 0; sub < 8; ++sub) {
            const int t = tb + sub;
            const int pA = (sub & 1) * 2048;

            // ---- pre-barrier: h_tilde + pack + A writes (LDS only) ----
            f32x4 htl;
#pragma unroll
            for (int r = 0; r < 4; ++r) {
                float v = dec[sub * 4 + r] * hreg[r];
                htl[r] = v;
                __bf16 h = (__bf16)v;
                As[pA + ew + r * 8] = h;
                As[pA + 1024 + ew + r * 8] = (__bf16)(v - (float)h);
            }
            if (sub == 7 && tb + 8 < TLEN) {
                // publish next chunk's x-frags (writes complete before next barrier)
#pragma unroll
                for (int i = 0; i < 3; ++i) if (xvalid[i]) {
                    float v = xst[i];
                    __bf16 h = (__bf16)v;
                    Ax[npar * 8192 + xw[i]] = h;
                    Ax[npar * 8192 + 512 + xw[i]] = (__bf16)(v - (float)h);
                }
            }

            __syncthreads();

            // ---- post-barrier ----
            if ((sub & 3) == 0 && t > 0 && tid < 64) {
                float s = PP4[tid] + PP4[64 + tid] + PP4[128 + tid] + PP4[192 + tid];
                out[(size_t)(b0g + (tid >> 2)) * TLEN + (t - 4) + (tid & 3)] = s + bout;
            }
            if (sub == 0 && tb + 8 < TLEN) {
#pragma unroll
                for (int r = 0; r < 4; ++r) {
                    *(float4*)&dtn[r * 8]     = *(const float4*)(dtp + (size_t)(b0g + B0 + r) * TLEN + tb + 8);
                    *(float4*)&dtn[r * 8 + 4] = *(const float4*)(dtp + (size_t)(b0g + B0 + r) * TLEN + tb + 12);
                }
            }
            if (sub == 1 && tb + 8 < TLEN) {
#pragma unroll
                for (int i = 0; i < 3; ++i) if (xvalid[i]) xst[i] = X[xg[i] + (tb + 8) * 5];
            }

            bf16x8 Ah0 = *(const bf16x8*)&As[pA + l * 8];
            bf16x8 Ah1 = *(const bf16x8*)&As[pA + 512 + l * 8];
            bf16x8 Al0 = *(const bf16x8*)&As[pA + 1024 + l * 8];
            bf16x8 Al1 = *(const bf16x8*)&As[pA + 1536 + l * 8];
            bf16x8 Axh = *(const bf16x8*)&Ax[par * 8192 + sub * 1024 + l * 8];
            bf16x8 Axl = *(const bf16x8*)&Ax[par * 8192 + sub * 1024 + 512 + l * 8];

            f32x4 accr, accz, accnh, accni;
#pragma unroll
            for (int g = 0; g < 3; ++g) {
                f32x4 c = {0.f, 0.f, 0.f, 0.f};
                f32x4 d = {0.f, 0.f, 0.f, 0.f};
                f32x4 e = {0.f, 0.f, 0.f, 0.f};
                c = MFMA(Ah0, Bh[g][0], c);
                c = MFMA(Al0, Bh[g][0], c);
                c = MFMA(Ah0, Bl[g][0], c);
                d = MFMA(Ah1, Bh[g][1], d);
                d = MFMA(Al1, Bh[g][1], d);
                d = MFMA(Ah1, Bl[g][1], d);
                e = MFMA(Axh, Bh[g][2], e);
                e = MFMA(Axl, Bh[g][2], e);
                e = MFMA(Axh, Bl[g][2], e);
                if (g == 0)      accr = c + d + e;
                else if (g == 1) accz = c + d + e;
                else           { accnh = c + d; accni = e; }
            }

            // gates + h update + pred partial
            float pr[4];
#pragma unroll
            for (int r = 0; r < 4; ++r) {
                float rr = sigmoid_f(accr[r]);
                float zz = sigmoid_f(accz[r]);
                float nn = tanh_f(accni[r] + rr * (accnh[r] + bias_nh));
                float hv = fmaf(zz, htl[r] - nn, nn);
                hreg[r] = hv;
                pr[r] = wout * hv;
            }

            // 16-lane butterfly reduce over hidden slice
#pragma unroll
            for (int m = 1; m <= 8; m <<= 1) {
#pragma unroll
                for (int r = 0; r < 4; ++r) pr[r] += __shfl_xor(pr[r], m, 64);
            }
#pragma unroll
            for (int r = 0; r < 4; ++r) pbuf[r][t & 3] = pr[r];

            if ((t & 3) == 3 && lane16 == 0) {
#pragma unroll
                for (int r = 0; r < 4; ++r) {
                    *(float4*)&PP4[(w * 16 + B0 + r) * 4] =
                        make_float4(pbuf[r][0], pbuf[r][1], pbuf[r][2], pbuf[r][3]);
                }
            }

            if (sub == 7 && tb + 8 < TLEN) {
#pragma unroll
                for (int t2 = 0; t2 < 8; ++t2)
#pragma unroll
                    for (int r = 0; r < 4; ++r)
                        dec[t2 * 4 + r] = __expf(-fmaxf(fmaf(dtn[r * 8 + t2], wdt, bdt), 0.f));
            }
        }
    }

    // final 4-t group combine
    __syncthreads();
    if (tid < 64) {
        float s = PP4[tid] + PP4[64 + tid] + PP4[128 + tid] + PP4[192 + tid];
        out[(size_t)(b0g + (tid >> 2)) * TLEN + (TLEN - 4) + (tid & 3)] = s + bout;
    }
}

extern "C" void kernel_launch(void* const* d_in, const int* in_sizes, int n_in,
                              void* d_out, int out_size, void* d_ws, size_t ws_size,
                              hipStream_t stream) {
    const float* X    = (const float*)d_in[0];
    const float* dt   = (const float*)d_in[1];
    const float* w_ih = (const float*)d_in[2];
    const float* w_hh = (const float*)d_in[3];
    const float* b_ih = (const float*)d_in[4];
    const float* b_hh = (const float*)d_in[5];
    const float* w_dt = (const float*)d_in[6];
    const float* b_dt = (const float*)d_in[7];
    const float* w_out = (const float*)d_in[8];
    const float* b_out = (const float*)d_in[9];
    float* out = (float*)d_out;

    grut1_kernel<<<dim3(4096 / BT), dim3(256), 0, stream>>>(
        X, dt, w_ih, w_hh, b_ih, b_hh, w_dt, b_dt, w_out, b_out, out);
}

// Round 5
// 457.883 us; speedup vs baseline: 1.6215x; 1.4395x over previous
//
#include <hip/hip_runtime.h>
#include <hip/hip_bf16.h>
#include <math.h>

typedef __bf16 bf16x8 __attribute__((ext_vector_type(8)));
typedef float f32x4 __attribute__((ext_vector_type(4)));

#define TLEN 512
#define FIN 5
#define BT 16

#define MFMA(a,b,c) __builtin_amdgcn_mfma_f32_16x16x32_bf16(a,b,c,0,0,0)
#define LOG2E 1.44269504f

__device__ __forceinline__ float sigmoid2_f(float x) {
    // rcp(1+exp2(-log2e*x)); correct limits at +-inf
    return __builtin_amdgcn_rcpf(1.f + __builtin_amdgcn_exp2f(-LOG2E * x));
}
__device__ __forceinline__ float tanh2_f(float x) {
    // 1 - 2*rcp(1+exp2(2*log2e*x)); correct limits at +-inf, no abs/copysign
    float t = __builtin_amdgcn_rcpf(1.f + __builtin_amdgcn_exp2f(2.f * LOG2E * x));
    return fmaf(-2.f, t, 1.f);
}
// sum over the 16-lane row (quad-local) via DPP row rotates — VALU-only
__device__ __forceinline__ float rowsum16(float x) {
    x += __int_as_float(__builtin_amdgcn_update_dpp(0, __float_as_int(x), 0x128, 0xf, 0xf, false));
    x += __int_as_float(__builtin_amdgcn_update_dpp(0, __float_as_int(x), 0x124, 0xf, 0xf, false));
    x += __int_as_float(__builtin_amdgcn_update_dpp(0, __float_as_int(x), 0x122, 0xf, 0xf, false));
    x += __int_as_float(__builtin_amdgcn_update_dpp(0, __float_as_int(x), 0x121, 0xf, 0xf, false));
    return x;
}

// 256 blocks x 256 threads. Block: 16 batches; wave w owns hidden [16w,16w+16).
// MFMA K=96: k 0..63 = h_tilde (hi/lo, 3-term split), k 64..95 = x/bias tile.
// One barrier/step (As double-buffered) + one barrier/8-step chunk (out combine).
// R5: single chained acc per gate (no c/d/e combine), DPP rotate-add reduce
// (no ds_swizzle), output combine once per chunk, exp2-form gates.
__global__ __launch_bounds__(256, 1) void grut1_kernel(
    const float* __restrict__ X, const float* __restrict__ dtp,
    const float* __restrict__ w_ih, const float* __restrict__ w_hh,
    const float* __restrict__ b_ih, const float* __restrict__ b_hh,
    const float* __restrict__ w_dt, const float* __restrict__ b_dt,
    const float* __restrict__ w_out, const float* __restrict__ b_out,
    float* __restrict__ out)
{
    __shared__ __align__(16) __bf16 As[4096];    // h~ frags: [phase2][hi/lo][kt2][512]
    __shared__ __align__(16) __bf16 Ax[16384];   // x frags: [parity2][t8][hi512|lo512]
    __shared__ __align__(16) float PPc[512];     // pred partials [wave4][b16][t8]

    const int tid = threadIdx.x;
    const int w = tid >> 6;
    const int l = tid & 63;
    const int lane16 = l & 15;
    const int quad = l >> 4;
    const int B0 = quad * 4;
    const int hh = w * 16 + lane16;
    const int b0g = blockIdx.x * BT;

    // A-frag write position for k = hh (fragment-linear, verified R1/R2)
    const int ew = (hh >> 5) * 512 + ((((hh & 31) >> 3) * 16) + B0) * 8 + (hh & 7);

    const float wdt = w_dt[hh];
    const float bdt = b_dt[hh];
    const float wout = w_out[hh];
    const float bout = b_out[0];
    const float bias_nh = b_hh[128 + hh];

    // B fragments: [gate][ktile 0..2], hi/lo split, VGPR-resident.
    bf16x8 Bh[3][3], Bl[3][3];
#pragma unroll
    for (int g = 0; g < 3; ++g) {
        const int j = g * 64 + hh;
#pragma unroll
        for (int kt = 0; kt < 2; ++kt) {
            const float* src = w_hh + j * 64 + kt * 32 + quad * 8;
            bf16x8 hi, lo;
#pragma unroll
            for (int i = 0; i < 8; ++i) {
                float v = src[i];
                __bf16 h = (__bf16)v;
                hi[i] = h;
                lo[i] = (__bf16)(v - (float)h);
            }
            Bh[g][kt] = hi;
            Bl[g][kt] = lo;
        }
        float biasg = (g == 2) ? b_ih[j] : (b_ih[j] + b_hh[j]);
        bf16x8 hi, lo;
#pragma unroll
        for (int i = 0; i < 8; ++i) {
            float v = 0.f;
            if (quad == 0) {
                if (i < 5) v = w_ih[j * 5 + i];
                else if (i == 5) v = biasg;
            }
            __bf16 h = (__bf16)v;
            hi[i] = h;
            lo[i] = (__bf16)(v - (float)h);
        }
        Bh[g][2] = hi;
        Bl[g][2] = lo;
    }

    // x staging map: element v in [0,640) -> (b = v/40, rem = v%40, t = rem/5, f = rem%5)
    int xg[3], xw[3], xvalid[3];
#pragma unroll
    for (int i = 0; i < 3; ++i) {
        int v = tid + i * 256;
        xvalid[i] = (v < 640);
        int vv = xvalid[i] ? v : 0;
        int b = vv / 40;
        int rem = vv - b * 40;
        int tt = rem / 5;
        int f = rem - tt * 5;
        xg[i] = (b0g + b) * (TLEN * FIN) + rem;
        xw[i] = tt * 1024 + b * 8 + f;
    }

    // ---- init: zero Ax, barrier, THEN ones column + chunk-0 x staging ----
    {
        float4 z4 = make_float4(0.f, 0.f, 0.f, 0.f);
        float4* p4 = (float4*)Ax;
#pragma unroll
        for (int i = 0; i < 8; ++i) p4[tid + i * 256] = z4;
    }
    __syncthreads();
    Ax[(tid >> 4) * 1024 + (tid & 15) * 8 + 5] = (__bf16)1.0f;
#pragma unroll
    for (int i = 0; i < 3; ++i) if (xvalid[i]) {
        float v = X[xg[i]];
        __bf16 h = (__bf16)v;
        Ax[xw[i]] = h;
        Ax[512 + xw[i]] = (__bf16)(v - (float)h);
    }

    // decay for chunk 0
    float dtn[32], dec[32];
#pragma unroll
    for (int r = 0; r < 4; ++r) {
        *(float4*)&dtn[r * 8]     = *(const float4*)(dtp + (size_t)(b0g + B0 + r) * TLEN);
        *(float4*)&dtn[r * 8 + 4] = *(const float4*)(dtp + (size_t)(b0g + B0 + r) * TLEN + 4);
    }
#pragma unroll
    for (int t2 = 0; t2 < 8; ++t2)
#pragma unroll
        for (int r = 0; r < 4; ++r)
            dec[t2 * 4 + r] = __builtin_amdgcn_exp2f(-LOG2E * fmaxf(fmaf(dtn[r * 8 + t2], wdt, bdt), 0.f));

    __syncthreads();

    f32x4 hreg = {0.f, 0.f, 0.f, 0.f};
    float pbuf[4][8];
    float xst[3];

#pragma unroll 1
    for (int tb = 0; tb < TLEN; tb += 8) {
        const int par = (tb >> 3) & 1;
        const int npar = par ^ 1;
#pragma unroll
        for (int sub = 0; sub < 8; ++sub) {
            const int pA = (sub & 1) * 2048;

            // ---- pre-barrier: h_tilde + pack + A writes (LDS only) ----
            f32x4 htl;
#pragma unroll
            for (int r = 0; r < 4; ++r) {
                float v = dec[sub * 4 + r] * hreg[r];
                htl[r] = v;
                __bf16 h = (__bf16)v;
                As[pA + ew + r * 8] = h;
                As[pA + 1024 + ew + r * 8] = (__bf16)(v - (float)h);
            }
            if (sub == 7 && tb + 8 < TLEN) {
                // publish next chunk's x-frags
#pragma unroll
                for (int i = 0; i < 3; ++i) if (xvalid[i]) {
                    float v = xst[i];
                    __bf16 h = (__bf16)v;
                    Ax[npar * 8192 + xw[i]] = h;
                    Ax[npar * 8192 + 512 + xw[i]] = (__bf16)(v - (float)h);
                }
            }

            __syncthreads();

            // ---- post-barrier: LDS reads first ----
            bf16x8 Ah0 = *(const bf16x8*)&As[pA + l * 8];
            bf16x8 Ah1 = *(const bf16x8*)&As[pA + 512 + l * 8];
            bf16x8 Al0 = *(const bf16x8*)&As[pA + 1024 + l * 8];
            bf16x8 Al1 = *(const bf16x8*)&As[pA + 1536 + l * 8];
            bf16x8 Axh = *(const bf16x8*)&Ax[par * 8192 + sub * 1024 + l * 8];
            bf16x8 Axl = *(const bf16x8*)&Ax[par * 8192 + sub * 1024 + 512 + l * 8];

            // prefetch (wave-uniform branches; latency hidden within the step)
            if (sub == 0 && tb + 8 < TLEN) {
#pragma unroll
                for (int r = 0; r < 4; ++r) {
                    *(float4*)&dtn[r * 8]     = *(const float4*)(dtp + (size_t)(b0g + B0 + r) * TLEN + tb + 8);
                    *(float4*)&dtn[r * 8 + 4] = *(const float4*)(dtp + (size_t)(b0g + B0 + r) * TLEN + tb + 12);
                }
            }
            if (sub == 1 && tb + 8 < TLEN) {
#pragma unroll
                for (int i = 0; i < 3; ++i) if (xvalid[i]) xst[i] = X[xg[i] + (tb + 8) * 5];
            }

            // ---- gh/gi via MFMA: single chained acc per gate, 4-way interleave ----
            f32x4 a0 = {0.f, 0.f, 0.f, 0.f};
            f32x4 a1 = {0.f, 0.f, 0.f, 0.f};
            f32x4 anh = {0.f, 0.f, 0.f, 0.f};
            f32x4 ani = {0.f, 0.f, 0.f, 0.f};
            a0  = MFMA(Ah0, Bh[0][0], a0);
            a1  = MFMA(Ah0, Bh[1][0], a1);
            anh = MFMA(Ah0, Bh[2][0], anh);
            ani = MFMA(Axh, Bh[2][2], ani);
            a0  = MFMA(Al0, Bh[0][0], a0);
            a1  = MFMA(Al0, Bh[1][0], a1);
            anh = MFMA(Al0, Bh[2][0], anh);
            ani = MFMA(Axl, Bh[2][2], ani);
            a0  = MFMA(Ah0, Bl[0][0], a0);
            a1  = MFMA(Ah0, Bl[1][0], a1);
            anh = MFMA(Ah0, Bl[2][0], anh);
            ani = MFMA(Axh, Bl[2][2], ani);
            a0  = MFMA(Ah1, Bh[0][1], a0);
            a1  = MFMA(Ah1, Bh[1][1], a1);
            anh = MFMA(Ah1, Bh[2][1], anh);
            a0  = MFMA(Al1, Bh[0][1], a0);
            a1  = MFMA(Al1, Bh[1][1], a1);
            anh = MFMA(Al1, Bh[2][1], anh);
            a0  = MFMA(Ah1, Bl[0][1], a0);
            a1  = MFMA(Ah1, Bl[1][1], a1);
            anh = MFMA(Ah1, Bl[2][1], anh);
            a0  = MFMA(Axh, Bh[0][2], a0);
            a1  = MFMA(Axh, Bh[1][2], a1);
            a0  = MFMA(Axl, Bh[0][2], a0);
            a1  = MFMA(Axl, Bh[1][2], a1);
            a0  = MFMA(Axh, Bl[0][2], a0);
            a1  = MFMA(Axh, Bl[1][2], a1);

            // gates + h update + pred partial (DPP row-sum, stored to pbuf regs)
#pragma unroll
            for (int r = 0; r < 4; ++r) {
                float rr = sigmoid2_f(a0[r]);
                float zz = sigmoid2_f(a1[r]);
                float nn = tanh2_f(ani[r] + rr * (anh[r] + bias_nh));
                float hv = fmaf(zz, htl[r] - nn, nn);
                hreg[r] = hv;
                pbuf[r][sub] = rowsum16(wout * hv);
            }

            if (sub == 7) {
                if (lane16 == 0) {
#pragma unroll
                    for (int r = 0; r < 4; ++r) {
                        f32x4 v0 = {pbuf[r][0], pbuf[r][1], pbuf[r][2], pbuf[r][3]};
                        f32x4 v1 = {pbuf[r][4], pbuf[r][5], pbuf[r][6], pbuf[r][7]};
                        *(f32x4*)&PPc[w * 128 + (B0 + r) * 8]     = v0;
                        *(f32x4*)&PPc[w * 128 + (B0 + r) * 8 + 4] = v1;
                    }
                }
                if (tb + 8 < TLEN) {
#pragma unroll
                    for (int t2 = 0; t2 < 8; ++t2)
#pragma unroll
                        for (int r = 0; r < 4; ++r)
                            dec[t2 * 4 + r] = __builtin_amdgcn_exp2f(
                                -LOG2E * fmaxf(fmaf(dtn[r * 8 + t2], wdt, bdt), 0.f));
                }
            }
        }

        // ---- chunk epilogue: combine + store 16b x 8t outputs ----
        __syncthreads();
        if (tid < 128) {
            int b = tid >> 3, t8 = tid & 7;
            int base = b * 8 + t8;
            float s = PPc[base] + PPc[128 + base] + PPc[256 + base] + PPc[384 + base];
            out[(size_t)(b0g + b) * TLEN + tb + t8] = s + bout;
        }
    }
}

extern "C" void kernel_launch(void* const* d_in, const int* in_sizes, int n_in,
                              void* d_out, int out_size, void* d_ws, size_t ws_size,
                              hipStream_t stream) {
    const float* X    = (const float*)d_in[0];
    const float* dt   = (const float*)d_in[1];
    const float* w_ih = (const float*)d_in[2];
    const float* w_hh = (const float*)d_in[3];
    const float* b_ih = (const float*)d_in[4];
    const float* b_hh = (const float*)d_in[5];
    const float* w_dt = (const float*)d_in[6];
    const float* b_dt = (const float*)d_in[7];
    const float* w_out = (const float*)d_in[8];
    const float* b_out = (const float*)d_in[9];
    float* out = (float*)d_out;

    grut1_kernel<<<dim3(4096 / BT), dim3(256), 0, stream>>>(
        X, dt, w_ih, w_hh, b_ih, b_hh, w_dt, b_dt, w_out, b_out, out);
}

// Round 6
// 399.371 us; speedup vs baseline: 1.8590x; 1.1465x over previous
//
#include <hip/hip_runtime.h>
#include <math.h>

typedef _Float16 f16x8 __attribute__((ext_vector_type(8)));
typedef _Float16 f16x4 __attribute__((ext_vector_type(4)));
typedef float f32x4 __attribute__((ext_vector_type(4)));

#define TLEN 512
#define BT 16
#define MFMA(a,b,c) __builtin_amdgcn_mfma_f32_16x16x32_f16(a,b,c,0,0,0)
#define LOG2E 1.44269504f

__device__ __forceinline__ float sigmoid2_f(float x) {
    return __builtin_amdgcn_rcpf(1.f + __builtin_amdgcn_exp2f(-LOG2E * x));
}
__device__ __forceinline__ float tanh2_f(float x) {
    float t = __builtin_amdgcn_rcpf(1.f + __builtin_amdgcn_exp2f(2.f * LOG2E * x));
    return fmaf(-2.f, t, 1.f);
}

// 256 blocks x 256 threads; block = 16 batches; wave w: out-hidden [16w,16w+16).
// SWAPPED operands: A = weights (VGPR-resident, fp16 hi/lo), B = state/x (LDS).
// C[m=hidden-local (quad*4+r)][n=batch (lane&15)]. Lane's h_new covers 4
// consecutive hidden -> next step's B-frag publish is ONE ds_write_b64/plane.
// K=64 state (2 ktiles, fp16 hi/lo) + K=32 x-tile (fp16 hi/lo). Biases are
// EXACT fp32 via MFMA C-seed. 27 MFMA/step, 3-term products (AhBh+AlBh+AhBl).
__global__ __launch_bounds__(256, 1) void grut1_kernel(
    const float* __restrict__ X, const float* __restrict__ dtp,
    const float* __restrict__ w_ih, const float* __restrict__ w_hh,
    const float* __restrict__ b_ih, const float* __restrict__ b_hh,
    const float* __restrict__ w_dt, const float* __restrict__ b_dt,
    const float* __restrict__ w_out, const float* __restrict__ b_out,
    float* __restrict__ out)
{
    __shared__ __align__(16) _Float16 Bs[4096];    // [phase2][plane2][kt2][512]
    __shared__ __align__(16) _Float16 Bx[16384];   // [par2][t8][plane2][512]
    __shared__ __align__(16) float PPc[512];       // [wave4][b16][t8]

    const int tid = threadIdx.x;
    const int w = tid >> 6;
    const int l = tid & 63;
    const int n16 = l & 15;       // batch lane
    const int quad = l >> 4;
    const int b0g = blockIdx.x * BT;
    const int hq0 = w * 16 + quad * 4;   // lane's first out-hidden (C rows)

    // B-state publish offset (halfwords): k_local = 16(w&1)+4q+r, contiguous r
    const int bsoff = (w >> 1) * 512
                    + (((2 * (w & 1) + (quad >> 1)) * 16) + n16) * 8
                    + (quad & 1) * 4;

    // per-lane constants (indexed by lane's 4 hidden rows)
    float wdt4[4], bdt4[4], wout4[4], biasNh[4];
    f32x4 seedR, seedZ, seedNi;
    const f32x4 zero4 = {0.f, 0.f, 0.f, 0.f};
#pragma unroll
    for (int r = 0; r < 4; ++r) {
        int j = hq0 + r;
        wdt4[r] = w_dt[j];
        bdt4[r] = b_dt[j];
        wout4[r] = w_out[j];
        seedR[r] = b_ih[j] + b_hh[j];
        seedZ[r] = b_ih[64 + j] + b_hh[64 + j];
        seedNi[r] = b_ih[128 + j];
        biasNh[r] = b_hh[128 + j];
    }
    const float bout = b_out[0];

    // A-frags (weights), fp16 hi/lo, VGPR-resident. A[m=l&15][k=quad*8+j].
    f16x8 Ah[3][2], Al[3][2], Axh[3], Axl[3];
#pragma unroll
    for (int g = 0; g < 3; ++g) {
        const int row = g * 64 + w * 16 + n16;
#pragma unroll
        for (int kt = 0; kt < 2; ++kt) {
            const float* src = w_hh + row * 64 + kt * 32 + quad * 8;
            f16x8 hi, lo;
#pragma unroll
            for (int i = 0; i < 8; ++i) {
                float v = src[i];
                _Float16 h = (_Float16)v;
                hi[i] = h;
                lo[i] = (_Float16)(v - (float)h);
            }
            Ah[g][kt] = hi;
            Al[g][kt] = lo;
        }
        f16x8 hi, lo;
#pragma unroll
        for (int i = 0; i < 8; ++i) {
            float v = (quad == 0 && i < 5) ? w_ih[row * 5 + i] : 0.f;
            _Float16 h = (_Float16)v;
            hi[i] = h;
            lo[i] = (_Float16)(v - (float)h);
        }
        Axh[g] = hi;
        Axl[g] = lo;
    }

    // x staging map: v in [0,640) -> b = v/40, rem = v%40, tt = rem/5, f = rem%5
    int xg[3], xw[3], xvalid[3];
#pragma unroll
    for (int i = 0; i < 3; ++i) {
        int v = tid + i * 256;
        xvalid[i] = (v < 640);
        int vv = xvalid[i] ? v : 0;
        int b = vv / 40;
        int rem = vv - b * 40;
        int tt = rem / 5;
        int f = rem - tt * 5;
        xg[i] = (b0g + b) * (TLEN * 5) + rem;
        xw[i] = tt * 1024 + b * 8 + f;
    }

    // zero Bx (unused K slots must be 0.0f16; avoids NaN from stale LDS)
    {
        float4 z4 = make_float4(0.f, 0.f, 0.f, 0.f);
        float4* p4 = (float4*)Bx;
#pragma unroll
        for (int i = 0; i < 8; ++i) p4[tid + i * 256] = z4;
    }
    __syncthreads();
    // publish chunk-0 x
#pragma unroll
    for (int i = 0; i < 3; ++i) if (xvalid[i]) {
        float v = X[xg[i]];
        _Float16 h = (_Float16)v;
        Bx[xw[i]] = h;
        Bx[512 + xw[i]] = (_Float16)(v - (float)h);
    }

    // chunk-0 dt (lane's batch) + dec for t=0
    const float* dtb = dtp + (size_t)(b0g + n16) * TLEN;
    float4 dtc0 = *(const float4*)(dtb);
    float4 dtc1 = *(const float4*)(dtb + 4);
    float4 dtn0, dtn1;
    float dcur[4];
#pragma unroll
    for (int r = 0; r < 4; ++r)
        dcur[r] = __builtin_amdgcn_exp2f(-LOG2E * fmaxf(fmaf(dtc0.x, wdt4[r], bdt4[r]), 0.f));

    f32x4 hreg = {0.f, 0.f, 0.f, 0.f};
    float pbuf[8];
    float xst[3];

#pragma unroll 1
    for (int tb = 0; tb < TLEN; tb += 8) {
        const int par = (tb >> 3) & 1;
        const int npar = par ^ 1;
#pragma unroll
        for (int sub = 0; sub < 8; ++sub) {
            const int pB = (sub & 1) * 2048;

            // ---- pre-barrier: h_tilde pack + state publish (2x ds_write_b64) ----
            f32x4 htl;
            f16x4 vh, vl;
#pragma unroll
            for (int r = 0; r < 4; ++r) {
                float v = dcur[r] * hreg[r];
                htl[r] = v;
                _Float16 h = (_Float16)v;
                vh[r] = h;
                vl[r] = (_Float16)(v - (float)h);
            }
            *(f16x4*)&Bs[pB + bsoff] = vh;
            *(f16x4*)&Bs[pB + 1024 + bsoff] = vl;
            if (sub == 7 && tb + 8 < TLEN) {
#pragma unroll
                for (int i = 0; i < 3; ++i) if (xvalid[i]) {
                    float v = xst[i];
                    _Float16 h = (_Float16)v;
                    Bx[npar * 8192 + xw[i]] = h;
                    Bx[npar * 8192 + 512 + xw[i]] = (_Float16)(v - (float)h);
                }
            }

            __syncthreads();

            // ---- post-barrier: B-frag reads ----
            f16x8 Bh0 = *(const f16x8*)&Bs[pB + l * 8];
            f16x8 Bh1 = *(const f16x8*)&Bs[pB + 512 + l * 8];
            f16x8 Bl0 = *(const f16x8*)&Bs[pB + 1024 + l * 8];
            f16x8 Bl1 = *(const f16x8*)&Bs[pB + 1536 + l * 8];
            f16x8 Bxh = *(const f16x8*)&Bx[par * 8192 + sub * 1024 + l * 8];
            f16x8 Bxl = *(const f16x8*)&Bx[par * 8192 + sub * 1024 + 512 + l * 8];

            // prev-chunk output combine (piggybacks on this barrier)
            if (sub == 0 && tb > 0 && tid < 128) {
                int b = tid >> 3, t8 = tid & 7;
                int base = b * 8 + t8;
                float s = PPc[base] + PPc[128 + base] + PPc[256 + base] + PPc[384 + base];
                out[(size_t)(b0g + b) * TLEN + (tb - 8) + t8] = s + bout;
            }
            // next-chunk prefetches (drain overlaps following steps)
            if (sub == 1 && tb + 8 < TLEN) {
#pragma unroll
                for (int i = 0; i < 3; ++i) if (xvalid[i]) xst[i] = X[xg[i] + (tb + 8) * 5];
            }
            if (sub == 2 && tb + 8 < TLEN) {
                dtn0 = *(const float4*)(dtb + tb + 8);
                dtn1 = *(const float4*)(dtb + tb + 12);
            }

            // ---- 27 MFMA, 4 chains (R:9, Z:9, Nh:6, Ni:3), bias-seeded ----
            f32x4 aR = seedR, aZ = seedZ, aNi = seedNi, aNh = zero4;
            aR  = MFMA(Ah[0][0], Bh0, aR);
            aZ  = MFMA(Ah[1][0], Bh0, aZ);
            aNh = MFMA(Ah[2][0], Bh0, aNh);
            aNi = MFMA(Axh[2], Bxh, aNi);
            aR  = MFMA(Al[0][0], Bh0, aR);
            aZ  = MFMA(Al[1][0], Bh0, aZ);
            aNh = MFMA(Al[2][0], Bh0, aNh);
            aNi = MFMA(Axl[2], Bxh, aNi);
            aR  = MFMA(Ah[0][0], Bl0, aR);
            aZ  = MFMA(Ah[1][0], Bl0, aZ);
            aNh = MFMA(Ah[2][0], Bl0, aNh);
            aNi = MFMA(Axh[2], Bxl, aNi);
            aR  = MFMA(Ah[0][1], Bh1, aR);
            aZ  = MFMA(Ah[1][1], Bh1, aZ);
            aNh = MFMA(Ah[2][1], Bh1, aNh);
            aR  = MFMA(Al[0][1], Bh1, aR);
            aZ  = MFMA(Al[1][1], Bh1, aZ);
            aNh = MFMA(Al[2][1], Bh1, aNh);
            aR  = MFMA(Ah[0][1], Bl1, aR);
            aZ  = MFMA(Ah[1][1], Bl1, aZ);
            aNh = MFMA(Ah[2][1], Bl1, aNh);
            aR  = MFMA(Axh[0], Bxh, aR);
            aZ  = MFMA(Axh[1], Bxh, aZ);
            aR  = MFMA(Axl[0], Bxh, aR);
            aZ  = MFMA(Axl[1], Bxh, aZ);
            aR  = MFMA(Axh[0], Bxl, aR);
            aZ  = MFMA(Axh[1], Bxl, aZ);

            // dec for t+1 (computed under MFMA shadow, consumed next pre-barrier)
            if (tb + 8 < TLEN || sub < 7) {
                float dnext = (sub == 0) ? dtc0.y : (sub == 1) ? dtc0.z : (sub == 2) ? dtc0.w
                            : (sub == 3) ? dtc1.x : (sub == 4) ? dtc1.y : (sub == 5) ? dtc1.z
                            : (sub == 6) ? dtc1.w : dtn0.x;
#pragma unroll
                for (int r = 0; r < 4; ++r)
                    dcur[r] = __builtin_amdgcn_exp2f(-LOG2E * fmaxf(fmaf(dnext, wdt4[r], bdt4[r]), 0.f));
            }

            // ---- gates + h update + pred ----
            float p = 0.f;
#pragma unroll
            for (int r = 0; r < 4; ++r) {
                float rr = sigmoid2_f(aR[r]);
                float zz = sigmoid2_f(aZ[r]);
                float nn = tanh2_f(aNi[r] + rr * (aNh[r] + biasNh[r]));
                float hv = fmaf(zz, htl[r] - nn, nn);
                hreg[r] = hv;
                p = fmaf(wout4[r], hv, p);
            }
            p += __shfl_xor(p, 16, 64);
            p += __shfl_xor(p, 32, 64);
            pbuf[sub] = p;

            if (sub == 7) {
                if (l < 16) {
                    f32x4 v0 = {pbuf[0], pbuf[1], pbuf[2], pbuf[3]};
                    f32x4 v1 = {pbuf[4], pbuf[5], pbuf[6], pbuf[7]};
                    *(f32x4*)&PPc[w * 128 + n16 * 8] = v0;
                    *(f32x4*)&PPc[w * 128 + n16 * 8 + 4] = v1;
                }
                dtc0 = dtn0;
                dtc1 = dtn1;
            }
        }
    }

    // final chunk combine
    __syncthreads();
    if (tid < 128) {
        int b = tid >> 3, t8 = tid & 7;
        int base = b * 8 + t8;
        float s = PPc[base] + PPc[128 + base] + PPc[256 + base] + PPc[384 + base];
        out[(size_t)(b0g + b) * TLEN + (TLEN - 8) + t8] = s + bout;
    }
}

extern "C" void kernel_launch(void* const* d_in, const int* in_sizes, int n_in,
                              void* d_out, int out_size, void* d_ws, size_t ws_size,
                              hipStream_t stream) {
    const float* X    = (const float*)d_in[0];
    const float* dt   = (const float*)d_in[1];
    const float* w_ih = (const float*)d_in[2];
    const float* w_hh = (const float*)d_in[3];
    const float* b_ih = (const float*)d_in[4];
    const float* b_hh = (const float*)d_in[5];
    const float* w_dt = (const float*)d_in[6];
    const float* b_dt = (const float*)d_in[7];
    const float* w_out = (const float*)d_in[8];
    const float* b_out = (const float*)d_in[9];
    float* out = (float*)d_out;

    grut1_kernel<<<dim3(4096 / BT), dim3(256), 0, stream>>>(
        X, dt, w_ih, w_hh, b_ih, b_hh, w_dt, b_dt, w_out, b_out, out);
}